// Round 1
// 1300.172 us; speedup vs baseline: 3.7065x; 3.7065x over previous
//
#include <hip/hip_runtime.h>
#include <cmath>

#define NB 2048
#define SS 50
#define DD 64
#define LL 500
#define KP 4
#define NI 100000

__device__ __forceinline__ float wsum(float v) {
#pragma unroll
    for (int m = 32; m >= 1; m >>= 1) v += __shfl_xor(v, m, 64);
    return v;
}
__device__ __forceinline__ float wmax(float v) {
#pragma unroll
    for (int m = 32; m >= 1; m >>= 1) v = fmaxf(v, __shfl_xor(v, m, 64));
    return v;
}

// y[s][lane] = sum_d xin[s][d] * W[d][lane]; logit[s] = sum_lane tanh(y)*wv[lane]
// s split across 4 waves (s = wave + 4*i).
// Register-lean: wr[8] chunks, dc loop NOT unrolled (unroll merged all wr chunks
// into 64+ live regs before -> 256-VGPR cap -> scratch spills = the 4.6 GB
// WRITE_SIZE pathology).
__device__ __forceinline__ void proj_logits(const float* xin,
                                            const float* __restrict__ W,
                                            const float* __restrict__ wv,
                                            float* lg, int wave, int lane) {
    float acc[13];
#pragma unroll
    for (int i = 0; i < 13; i++) acc[i] = 0.f;
#pragma unroll 1
    for (int dc = 0; dc < DD; dc += 8) {
        float wr[8];
#pragma unroll
        for (int t = 0; t < 8; t++) wr[t] = W[(dc + t) * DD + lane];
#pragma unroll
        for (int i = 0; i < 13; i++) {
            int s = wave + 4 * i;
            if (s < SS) {
                const float4* xr = reinterpret_cast<const float4*>(xin + s * DD + dc);
#pragma unroll
                for (int q = 0; q < 2; q++) {
                    float4 xv = xr[q];
                    acc[i] = fmaf(xv.x, wr[4 * q + 0], acc[i]);
                    acc[i] = fmaf(xv.y, wr[4 * q + 1], acc[i]);
                    acc[i] = fmaf(xv.z, wr[4 * q + 2], acc[i]);
                    acc[i] = fmaf(xv.w, wr[4 * q + 3], acc[i]);
                }
            }
        }
    }
    float wl = wv[lane];
#pragma unroll
    for (int i = 0; i < 13; i++) {
        int s = wave + 4 * i;
        if (s < SS) {
            float v = tanhf(acc[i]) * wl;
            v = wsum(v);
            if (lane == 0) lg[s] = v;
        }
    }
}

__global__ __launch_bounds__(256, 3) void sine_main(
    const int* __restrict__ item_seq,
    const float* __restrict__ emb,
    const float* __restrict__ Cm,
    const float* __restrict__ w1, const float* __restrict__ w2,
    const float* __restrict__ w3, const float* __restrict__ w4,
    const float* __restrict__ wk1, const float* __restrict__ wk2,
    const float* __restrict__ ln2w, const float* __restrict__ ln2b,
    const float* __restrict__ ln4w, const float* __restrict__ ln4b,
    float* __restrict__ vu_out) {
    __shared__ float xu[SS][DD];   // reused as x_u_bar after delta_k (xu dead then)
    __shared__ float su[LL];
    __shared__ float lg[SS];
    __shared__ float aw[SS];
    __shared__ float zu[DD];
    __shared__ float cu[KP][DD];
    __shared__ float cun[KP][DD];
    __shared__ float pkt[SS][KP];
    __shared__ float ptk[KP][SS];
    __shared__ float dlt[KP][DD];
    __shared__ float capt[DD];
    __shared__ float eks[KP];
    __shared__ int sidx[SS];
    __shared__ int tidx[KP];
    __shared__ float tval[KP];

    const int tid = threadIdx.x, wave = tid >> 6, lane = tid & 63;
    const int b = blockIdx.x;

    if (tid < SS) sidx[tid] = item_seq[b * SS + tid];
    __syncthreads();

    // gather x_u = item_emb[item_seq[b]]  (S x D)
    for (int i = tid; i < SS * (DD / 4); i += 256) {
        int s = i >> 4, c = i & 15;
        float4 v = reinterpret_cast<const float4*>(emb + (size_t)sidx[s] * DD)[c];
        reinterpret_cast<float4*>(&xu[s][0])[c] = v;
    }
    __syncthreads();

    // x = tanh(x_u @ w1) @ w2 ; a = softmax_s(x)
    proj_logits(&xu[0][0], w1, w2, lg, wave, lane);
    __syncthreads();
    if (wave == 0) {
        float v = (lane < SS) ? lg[lane] : -INFINITY;
        float mx = wmax(v);
        float e = (lane < SS) ? expf(v - mx) : 0.f;
        float sm = wsum(e);
        if (lane < SS) aw[lane] = e / sm;
    }
    __syncthreads();

    // z_u[d] = sum_s a[s]*x_u[s][d]
    if (tid < DD) {
        float z = 0.f;
        for (int s = 0; s < SS; s++) z = fmaf(aw[s], xu[s][tid], z);
        zu[tid] = z;
    }
    __syncthreads();

    // s_u = z_u @ C^T  (L)
    for (int l = tid; l < LL; l += 256) {
        const float* cr = Cm + (size_t)l * DD;
        float a0 = 0.f;
        for (int d = 0; d < DD; d++) a0 = fmaf(zu[d], cr[d], a0);
        su[l] = a0;
    }
    __syncthreads();

    // top-K (ascending order like argsort[:, -K:]; ties -> larger index)
    for (int p = 0; p < KP; p++) {
        float bv = -INFINITY;
        int bi = -1;
        for (int l = lane; l < LL; l += 64) {
            float v = su[l];
            if (v > bv || (v == bv && l > bi)) { bv = v; bi = l; }
        }
#pragma unroll
        for (int m = 32; m >= 1; m >>= 1) {
            float ov = __shfl_xor(bv, m, 64);
            int oi = __shfl_xor(bi, m, 64);
            if (ov > bv || (ov == bv && oi > bi)) { bv = ov; bi = oi; }
        }
        if (tid == 0) { tidx[KP - 1 - p] = bi; tval[KP - 1 - p] = bv; su[bi] = -INFINITY; }
        __syncthreads();
    }

    // C_u = C[idx]*sigmoid(s_top); C_u_norm = layernorm(C_u)  (wave k handles row k)
    {
        int k = wave;
        float sv = tval[k];
        float sg = 1.f / (1.f + expf(-sv));
        float c = Cm[(size_t)tidx[k] * DD + lane] * sg;
        cu[k][lane] = c;
        float mean = wsum(c) * (1.f / DD);
        float dv = c - mean;
        float var = wsum(dv * dv) * (1.f / DD);
        float nv = dv / sqrtf(var + 1e-12f);
        cun[k][lane] = nv * ln2w[lane] + ln2b[lane];
    }
    __syncthreads();

    // w3_x_u_norm = l2norm(x_u @ w3); P_k_t = <.,C_u_norm>; softmax over k
    {
        float acc[13];
#pragma unroll
        for (int i = 0; i < 13; i++) acc[i] = 0.f;
#pragma unroll 1
        for (int dc = 0; dc < DD; dc += 8) {
            float wr[8];
#pragma unroll
            for (int t = 0; t < 8; t++) wr[t] = w3[(dc + t) * DD + lane];
#pragma unroll
            for (int i = 0; i < 13; i++) {
                int s = wave + 4 * i;
                if (s < SS) {
                    const float4* xr = reinterpret_cast<const float4*>(&xu[s][dc]);
#pragma unroll
                    for (int q = 0; q < 2; q++) {
                        float4 xv = xr[q];
                        acc[i] = fmaf(xv.x, wr[4 * q + 0], acc[i]);
                        acc[i] = fmaf(xv.y, wr[4 * q + 1], acc[i]);
                        acc[i] = fmaf(xv.z, wr[4 * q + 2], acc[i]);
                        acc[i] = fmaf(xv.w, wr[4 * q + 3], acc[i]);
                    }
                }
            }
        }
#pragma unroll
        for (int i = 0; i < 13; i++) {
            int s = wave + 4 * i;
            if (s < SS) {
                float y = acc[i];
                float n2 = wsum(y * y);
                float yn = y / fmaxf(sqrtf(n2), 1e-12f);
                float p0 = wsum(yn * cun[0][lane]);
                float p1 = wsum(yn * cun[1][lane]);
                float p2 = wsum(yn * cun[2][lane]);
                float p3 = wsum(yn * cun[3][lane]);
                if (lane == 0) {
                    float mx = fmaxf(fmaxf(p0, p1), fmaxf(p2, p3));
                    float e0 = expf(p0 - mx), e1 = expf(p1 - mx);
                    float e2 = expf(p2 - mx), e3 = expf(p3 - mx);
                    float sm = e0 + e1 + e2 + e3;
                    pkt[s][0] = e0 / sm; pkt[s][1] = e1 / sm;
                    pkt[s][2] = e2 / sm; pkt[s][3] = e3 / sm;
                }
            }
        }
    }
    __syncthreads();

    // P_t_k: per-interest position attention (wave = k). s-chunks of 10, wr[8]:
    // keeps worst-case live regs ~100 (was acc[25]+wr[16] fully unrolled -> spill).
    {
        int k = wave;
        const float* Wk = wk1 + (size_t)k * DD * DD;
        float wl = wk2[k * DD + lane];
#pragma unroll 1
        for (int sc = 0; sc < SS; sc += 10) {
            float acc[10];
#pragma unroll
            for (int i = 0; i < 10; i++) acc[i] = 0.f;
#pragma unroll 1
            for (int dc = 0; dc < DD; dc += 8) {
                float wr[8];
#pragma unroll
                for (int t = 0; t < 8; t++) wr[t] = Wk[(dc + t) * DD + lane];
#pragma unroll
                for (int i = 0; i < 10; i++) {
                    const float4* xr = reinterpret_cast<const float4*>(&xu[sc + i][dc]);
#pragma unroll
                    for (int q = 0; q < 2; q++) {
                        float4 xv = xr[q];
                        acc[i] = fmaf(xv.x, wr[4 * q + 0], acc[i]);
                        acc[i] = fmaf(xv.y, wr[4 * q + 1], acc[i]);
                        acc[i] = fmaf(xv.z, wr[4 * q + 2], acc[i]);
                        acc[i] = fmaf(xv.w, wr[4 * q + 3], acc[i]);
                    }
                }
            }
#pragma unroll
            for (int i = 0; i < 10; i++) {
                float v = tanhf(acc[i]) * wl;
                v = wsum(v);
                if (lane == 0) ptk[k][sc + i] = v;
            }
        }
    }
    __syncthreads();
    {   // softmax over s per k
        int k = wave;
        float v = (lane < SS) ? ptk[k][lane] : -INFINITY;
        float mx = wmax(v);
        float e = (lane < SS) ? expf(v - mx) : 0.f;
        float sm = wsum(e);
        if (lane < SS) ptk[k][lane] = e / sm;
    }
    __syncthreads();

    // delta_k = l2norm(sum_s pkt[s][k]*ptk[k][s]*x_u[s])
    {
        int k = wave;
        float a0 = 0.f;
        for (int s = 0; s < SS; s++) {
            float m = pkt[s][k] * ptk[k][s];
            a0 = fmaf(m, xu[s][lane], a0);
        }
        float n2 = wsum(a0 * a0);
        dlt[k][lane] = a0 / fmaxf(sqrtf(n2), 1e-12f);
    }
    __syncthreads();

    // x_u_bar[s][d] = sum_k pkt[s][k]*C_u[k][d]  — overwrite xu (dead from here)
    for (int i = tid; i < SS * DD; i += 256) {
        int s = i >> 6, d = i & 63;
        xu[s][d] = pkt[s][0] * cu[0][d] + pkt[s][1] * cu[1][d] +
                   pkt[s][2] * cu[2][d] + pkt[s][3] * cu[3][d];
    }
    __syncthreads();

    // C_apt = layernorm(sum_s softmax_s(tanh(x_u_bar@w3)@w4) * x_u_bar)
    proj_logits(&xu[0][0], w3, w4, lg, wave, lane);
    __syncthreads();
    if (wave == 0) {
        float v = (lane < SS) ? lg[lane] : -INFINITY;
        float mx = wmax(v);
        float e = (lane < SS) ? expf(v - mx) : 0.f;
        float sm = wsum(e);
        if (lane < SS) aw[lane] = e / sm;
    }
    __syncthreads();
    if (tid < DD) {
        float z = 0.f;
        for (int s = 0; s < SS; s++) z = fmaf(aw[s], xu[s][tid], z);
        float mean = wsum(z) * (1.f / DD);
        float dv = z - mean;
        float var = wsum(dv * dv) * (1.f / DD);
        capt[tid] = dv / sqrtf(var + 1e-12f) * ln4w[tid] + ln4b[tid];
    }
    __syncthreads();

    // e_k softmax, v_u
    {
        int k = wave;
        float v = dlt[k][lane] * capt[lane];
        v = wsum(v);
        if (lane == 0) eks[k] = v * 10.f;  // /TAU, TAU=0.1
    }
    __syncthreads();
    if (tid < DD) {
        float e0 = eks[0], e1 = eks[1], e2 = eks[2], e3 = eks[3];
        float mx = fmaxf(fmaxf(e0, e1), fmaxf(e2, e3));
        float x0 = expf(e0 - mx), x1 = expf(e1 - mx);
        float x2 = expf(e2 - mx), x3 = expf(e3 - mx);
        float sm = x0 + x1 + x2 + x3;
        float vu = (x0 * dlt[0][tid] + x1 * dlt[1][tid] +
                    x2 * dlt[2][tid] + x3 * dlt[3][tid]) / sm;
        vu_out[(size_t)b * DD + tid] = vu;
    }
}

// scores[b][n] = v_u[b] . emb[n]   (32 b-rows x 256 n per block: halves the
// uncoalesced emb re-reads and loads-per-output vs the 16-row version)
__global__ __launch_bounds__(256) void sine_scores(const float* __restrict__ vu,
                                                   const float* __restrict__ emb,
                                                   float* __restrict__ out) {
    const int btile = blockIdx.x;
    const int n = blockIdx.y * 256 + threadIdx.x;
    if (n >= NI) return;
    float acc[32];
#pragma unroll
    for (int i = 0; i < 32; i++) acc[i] = 0.f;
    const float4* er = reinterpret_cast<const float4*>(emb + (size_t)n * DD);
    const float* vb = vu + (size_t)btile * 32 * DD;
#pragma unroll
    for (int dc = 0; dc < 16; dc++) {
        float4 e = er[dc];
#pragma unroll
        for (int i = 0; i < 32; i++) {
            const float* vr = vb + i * DD + dc * 4;  // block-uniform -> s_load
            acc[i] = fmaf(e.x, vr[0], acc[i]);
            acc[i] = fmaf(e.y, vr[1], acc[i]);
            acc[i] = fmaf(e.z, vr[2], acc[i]);
            acc[i] = fmaf(e.w, vr[3], acc[i]);
        }
    }
    size_t base = (size_t)btile * 32 * NI + n;
#pragma unroll
    for (int i = 0; i < 32; i++) out[base + (size_t)i * NI] = acc[i];
}

extern "C" void kernel_launch(void* const* d_in, const int* in_sizes, int n_in,
                              void* d_out, int out_size, void* d_ws, size_t ws_size,
                              hipStream_t stream) {
    const int* item_seq = (const int*)d_in[0];
    // d_in[1] = item_seq_len (unused by forward)
    const float* emb = (const float*)d_in[2];
    const float* Cm = (const float*)d_in[3];
    const float* w1 = (const float*)d_in[4];
    const float* w2 = (const float*)d_in[5];
    const float* w3 = (const float*)d_in[6];
    const float* w4 = (const float*)d_in[7];
    const float* wk1 = (const float*)d_in[8];
    const float* wk2 = (const float*)d_in[9];
    const float* ln2w = (const float*)d_in[10];
    const float* ln2b = (const float*)d_in[11];
    const float* ln4w = (const float*)d_in[12];
    const float* ln4b = (const float*)d_in[13];
    float* out = (float*)d_out;
    float* vu = (float*)d_ws;  // NB*DD floats = 512 KB

    sine_main<<<NB, 256, 0, stream>>>(item_seq, emb, Cm, w1, w2, w3, w4,
                                      wk1, wk2, ln2w, ln2b, ln4w, ln4b, vu);
    dim3 g2(NB / 32, (NI + 255) / 256);
    sine_scores<<<g2, 256, 0, stream>>>(vu, emb, out);
}